// Round 1
// baseline (4362.612 us; speedup 1.0000x reference)
//
#include <hip/hip_runtime.h>
#include <hip/hip_bf16.h>

// LSTM chain: B=256, S=512, H=256, V=128.
// Strategy:
//   prep kernel:  zx[v][4H] = emb[v] @ W[H:2H] + b   (token-indexed input projection,
//                 only 128 distinct tokens) ; Wb = W[0:H] repacked to bf16 in
//                 MFMA B-fragment order (one 1KB linear coalesced load per fragment).
//   seq kernel:   16 blocks x 512 threads (8 waves). Block owns 16 batch rows.
//                 Per step: z[16,1024] = h[16,256] @ Wh (bf16 MFMA 16x16x32, fp32 acc)
//                 + zx[token] ; gates in fp32 ; c in registers ; h written back to LDS
//                 directly in A-fragment layout (ping-pong buffers, 1 barrier/step).
// A/B fragment k-order uses one consistent bijection k = 32*s + 8*(lane>>4) + elem on
// both operands, so correctness is independent of the true HW intra-fragment k-perm.
// C/D layout (HW-verified): col = lane&15, row = 4*(lane>>4) + reg.

#define HID    256
#define FOURH  1024
#define SLEN   512
#define NBATCH 256
#define NVOCAB 128
#define BSZ    16     // batch rows per block

typedef __attribute__((ext_vector_type(8))) __bf16 bf16x8;
typedef __attribute__((ext_vector_type(4))) float  f32x4;

__device__ __forceinline__ unsigned short f2bf(float x) {
  unsigned int u = __builtin_bit_cast(unsigned int, x);
  u = (u + 0x7FFFu + ((u >> 16) & 1u)) >> 16;   // RNE
  return (unsigned short)u;
}
__device__ __forceinline__ float sigmoid_(float x) {
  // 1/(1+e^-x); v_exp + v_rcp. Correct limits at +-inf.
  return __builtin_amdgcn_rcpf(1.f + __expf(-x));
}
__device__ __forceinline__ float tanh_(float x) {
  // 1 - 2/(e^{2x}+1); correct limits at +-inf.
  return 1.f - 2.f * __builtin_amdgcn_rcpf(__expf(2.f * x) + 1.f);
}

// ---------------- prep: zx table + Wh bf16 fragment repack ----------------
__global__ __launch_bounds__(256) void lstm_prep(
    const float* __restrict__ emb, const float* __restrict__ W,
    const float* __restrict__ b, float* __restrict__ zx,
    unsigned short* __restrict__ Wb)
{
  const int blk = blockIdx.x;
  if (blk < NVOCAB) {
    // zx[v][col] = sum_k emb[v][k] * W[(H+k)][col] + b[col]
    __shared__ float ev[HID];
    const int v = blk;
    for (int i = threadIdx.x; i < HID; i += 256) ev[i] = emb[v * HID + i];
    __syncthreads();
    for (int jj = 0; jj < 4; ++jj) {
      const int col = jj * 256 + threadIdx.x;
      float acc = b[col];
      #pragma unroll 4
      for (int k = 0; k < HID; ++k)
        acc += ev[k] * W[(HID + k) * FOURH + col];   // coalesced across threads
      zx[v * FOURH + col] = acc;
    }
  } else {
    // Wb fragment layout: frag(tile c, kstep s): element (g, r, j) at
    //   (((c*8+s)*4+g)*16+r)*8 + j  holds  Wh[k = 32s+8g+j][zcol = 16c+r]
    // => per-lane load in seq kernel is base + lane*16B (fully linear 1KB).
    int idx = (blk - NVOCAB) * 256 + threadIdx.x;    // 0..32767 = (c,s,g,r)
    const int c = idx >> 9;
    const int rem = idx & 511;
    const int s = rem >> 6, gg = (rem >> 4) & 3, r = rem & 15;
    const int col = 16 * c + r;
    #pragma unroll
    for (int j = 0; j < 8; ++j) {
      const int k = 32 * s + 8 * gg + j;
      Wb[(((c * 8 + s) * 4 + gg) * 16 + r) * 8 + j] = f2bf(W[k * FOURH + col]);
    }
  }
}

// ---------------- sequential recurrence ----------------
__global__ __launch_bounds__(512, 2) void lstm_seq(
    const int* __restrict__ tokens, const float* __restrict__ zx,
    const unsigned short* __restrict__ Wb, float* __restrict__ out)
{
  // h fragments, ping-pong: element ((s*4+g)*16+r)*8+j = h[row=r][k=32s+8g+j] (bf16)
  __shared__ __align__(16) unsigned short hbuf[2][4096];
  const int tid = threadIdx.x;
  const int w = tid >> 6, l = tid & 63;
  const int g = l >> 4, r = l & 15;
  const int b0 = blockIdx.x * BSZ;
  const int row4 = 4 * g;                 // local row base (D-frag rows 4g+j)
  const int cb0 = 2 * w;                  // this wave owns h-col blocks cb0, cb0+1

  for (int i = tid; i < 2 * 4096; i += 512) ((unsigned short*)hbuf)[i] = 0;  // h0 = 0
  __syncthreads();

  float cst[2][4];                        // c state, registers: [cb][row j]
  #pragma unroll
  for (int cb = 0; cb < 2; ++cb)
    #pragma unroll
    for (int j = 0; j < 4; ++j) cst[cb][j] = 0.f;

  const unsigned short* wlane = Wb + l * 8;  // per-lane B-frag base

  for (int t = 0; t < SLEN; ++t) {
    const int pp = t & 1;

    // -- hoisted token + zx gather (hides L2 latency under MFMAs below) --
    int tok[4];
    #pragma unroll
    for (int j = 0; j < 4; ++j)
      tok[j] = tokens[(b0 + row4 + j) * SLEN + t];
    float zxv[2][4][4];                   // [cb][gate q][row j]
    #pragma unroll
    for (int j = 0; j < 4; ++j) {
      const float* zrow = zx + tok[j] * FOURH + r;
      #pragma unroll
      for (int cb = 0; cb < 2; ++cb) {
        const int col16 = (cb0 + cb) * 16;
        #pragma unroll
        for (int q = 0; q < 4; ++q)
          zxv[cb][q][j] = zrow[q * 256 + col16];
      }
    }

    // -- A fragments: 8 x ds_read_b128, perfectly linear (conflict-free) --
    bf16x8 a[8];
    #pragma unroll
    for (int s = 0; s < 8; ++s)
      a[s] = *reinterpret_cast<const bf16x8*>(&hbuf[pp][(s * 64 + l) * 8]);

    // -- 8 z-tiles (cb,q), B double-buffered from L2-resident Wb --
    f32x4 acc[2][4];
    bf16x8 bfrag[2][8];
    {
      const unsigned short* wp0 = wlane + (size_t)(16 * 0 + cb0 + 0) * 4096;
      #pragma unroll
      for (int s = 0; s < 8; ++s)
        bfrag[0][s] = *reinterpret_cast<const bf16x8*>(wp0 + s * 512);
    }
    #pragma unroll
    for (int u = 0; u < 8; ++u) {
      const int cb = u & 1, q = u >> 1;
      if (u < 7) {
        const int un = u + 1;
        const unsigned short* wpn =
            wlane + (size_t)(16 * (un >> 1) + cb0 + (un & 1)) * 4096;
        #pragma unroll
        for (int s = 0; s < 8; ++s)
          bfrag[un & 1][s] = *reinterpret_cast<const bf16x8*>(wpn + s * 512);
      }
      f32x4 A = {0.f, 0.f, 0.f, 0.f};
      #pragma unroll
      for (int s = 0; s < 8; ++s)
        A = __builtin_amdgcn_mfma_f32_16x16x32_bf16(a[s], bfrag[u & 1][s], A, 0, 0, 0);
      acc[cb][q] = A;
    }

    // -- gates (fp32), c in regs, write h to out + next A-fragments --
    #pragma unroll
    for (int cb = 0; cb < 2; ++cb) {
      const int cbi = cb0 + cb;
      const int col = 16 * cbi + r;               // h column 0..255
      const int s = col >> 5, gg = (col >> 3) & 3, jj = col & 7;
      #pragma unroll
      for (int j = 0; j < 4; ++j) {
        const float zi = acc[cb][0][j] + zxv[cb][0][j];
        const float zf = acc[cb][1][j] + zxv[cb][1][j];
        const float zo = acc[cb][2][j] + zxv[cb][2][j];
        const float zu = acc[cb][3][j] + zxv[cb][3][j];
        const float iv = sigmoid_(zi);
        const float fv = sigmoid_(zf);
        const float ov = sigmoid_(zo);
        const float uv = tanh_(zu);
        const float cn = iv * uv + fv * cst[cb][j];
        cst[cb][j] = cn;
        const float hn = ov * tanh_(cn);
        out[(size_t)(b0 + row4 + j) * (SLEN * HID) + (size_t)t * HID + col] = hn;
        hbuf[pp ^ 1][((s * 4 + gg) * 16 + (row4 + j)) * 8 + jj] = f2bf(hn);
      }
    }
    __syncthreads();   // single barrier/step (ping-pong makes it sufficient)
  }
}

extern "C" void kernel_launch(void* const* d_in, const int* in_sizes, int n_in,
                              void* d_out, int out_size, void* d_ws, size_t ws_size,
                              hipStream_t stream) {
  const int*   tokens = (const int*)d_in[0];
  const float* emb    = (const float*)d_in[1];
  const float* W      = (const float*)d_in[2];
  const float* b      = (const float*)d_in[3];
  float* out = (float*)d_out;

  float*          zx = (float*)d_ws;                                  // 512 KB
  unsigned short* Wb = (unsigned short*)((char*)d_ws + 512 * 1024);   // 512 KB

  lstm_prep<<<256, 256, 0, stream>>>(emb, W, b, zx, Wb);
  lstm_seq<<<16, 512, 0, stream>>>(tokens, zx, Wb, out);
}

// Round 2
// 3700.267 us; speedup vs baseline: 1.1790x; 1.1790x over previous
//
#include <hip/hip_runtime.h>
#include <hip/hip_bf16.h>

// LSTM chain: B=256, S=512, H=256, V=128.
// Round 2: W fully VGPR-resident.
//   prep kernel:  zx[v][4H] = emb[v] @ W[H:2H] + b ; Wb = W[0:H] repacked to bf16
//                 in MFMA B-fragment order (1KB linear per fragment).
//   seq kernel:   16 blocks x 1024 threads (16 waves, 4/SIMD). Block owns 16 batch
//                 rows. Wave w holds the B-fragments for z-tiles {q, cb=w}, q=0..3
//                 (32 frags = 128 VGPRs) loaded ONCE -> zero per-step W traffic.
//                 Per step: 8x ds_read_b128 A-frags from LDS ping-pong, 32 MFMA,
//                 gates fp32, c in regs, h written back in A-fragment layout.
// A/B fragment k-order uses one consistent bijection k = 32*s + 8*(lane>>4) + elem
// on both operands (correct for any true HW intra-fragment k-perm).
// C/D layout (HW-verified): col = lane&15, row = 4*(lane>>4) + reg.

#define HID    256
#define FOURH  1024
#define SLEN   512
#define NVOCAB 128
#define BSZ    16     // batch rows per block

typedef __attribute__((ext_vector_type(8))) __bf16 bf16x8;
typedef __attribute__((ext_vector_type(4))) float  f32x4;

__device__ __forceinline__ unsigned short f2bf(float x) {
  unsigned int u = __builtin_bit_cast(unsigned int, x);
  u = (u + 0x7FFFu + ((u >> 16) & 1u)) >> 16;   // RNE
  return (unsigned short)u;
}
__device__ __forceinline__ float sigmoid_(float x) {
  return __builtin_amdgcn_rcpf(1.f + __expf(-x));
}
__device__ __forceinline__ float tanh_(float x) {
  return 1.f - 2.f * __builtin_amdgcn_rcpf(__expf(2.f * x) + 1.f);
}

// ---------------- prep: zx table + Wh bf16 fragment repack ----------------
__global__ __launch_bounds__(256) void lstm_prep(
    const float* __restrict__ emb, const float* __restrict__ W,
    const float* __restrict__ b, float* __restrict__ zx,
    unsigned short* __restrict__ Wb)
{
  const int blk = blockIdx.x;
  if (blk < NVOCAB) {
    // zx[v][col] = sum_k emb[v][k] * W[(H+k)][col] + b[col]
    __shared__ float ev[HID];
    const int v = blk;
    for (int i = threadIdx.x; i < HID; i += 256) ev[i] = emb[v * HID + i];
    __syncthreads();
    for (int jj = 0; jj < 4; ++jj) {
      const int col = jj * 256 + threadIdx.x;
      float acc = b[col];
      #pragma unroll 4
      for (int k = 0; k < HID; ++k)
        acc += ev[k] * W[(HID + k) * FOURH + col];   // coalesced across threads
      zx[v * FOURH + col] = acc;
    }
  } else {
    // Wb fragment layout: frag(tile c, kstep s): element (g, r, j) at
    //   (((c*8+s)*4+g)*16+r)*8 + j  holds  Wh[k = 32s+8g+j][zcol = 16c+r]
    int idx = (blk - NVOCAB) * 256 + threadIdx.x;    // 0..32767 = (c,s,g,r)
    const int c = idx >> 9;
    const int rem = idx & 511;
    const int s = rem >> 6, gg = (rem >> 4) & 3, r = rem & 15;
    const int col = 16 * c + r;
    #pragma unroll
    for (int j = 0; j < 8; ++j) {
      const int k = 32 * s + 8 * gg + j;
      Wb[(((c * 8 + s) * 4 + gg) * 16 + r) * 8 + j] = f2bf(W[k * FOURH + col]);
    }
  }
}

// ---------------- sequential recurrence ----------------
__global__ __launch_bounds__(1024, 4) void lstm_seq(
    const int* __restrict__ tokens, const float* __restrict__ zx,
    const unsigned short* __restrict__ Wb, float* __restrict__ out)
{
  // h fragments, ping-pong: element ((s*4+g)*16+r)*8+j = h[row=r][k=32s+8g+j] (bf16)
  __shared__ __align__(16) unsigned short hbuf[2][4096];
  const int tid = threadIdx.x;
  const int w = tid >> 6, l = tid & 63;
  const int g = l >> 4, r = l & 15;
  const int b0 = blockIdx.x * BSZ;
  const int row4 = 4 * g;                 // D-frag local row base (rows 4g+j)

  for (int i = tid; i < 2 * 4096; i += 1024) ((unsigned short*)hbuf)[i] = 0;  // h0=0

  // --- W fragments resident in VGPRs for the entire sequence ---
  // wave w owns z-tiles (q, cb=w) -> tile index c = 16q + w; 32 frags = 128 VGPRs.
  bf16x8 wf[32];
  const unsigned short* wl = Wb + (size_t)l * 8;
  #pragma unroll
  for (int q = 0; q < 4; ++q)
    #pragma unroll
    for (int s = 0; s < 8; ++s)
      wf[q * 8 + s] = *reinterpret_cast<const bf16x8*>(
          wl + (size_t)(16 * q + w) * 4096 + s * 512);

  float cst[4] = {0.f, 0.f, 0.f, 0.f};    // c state (rows 4g+j, col colw)

  const int colw = 16 * w + r;            // this thread's h column 0..255
  const int s4 = colw >> 5, gg = (colw >> 3) & 3, jj = colw & 7;

  __syncthreads();

  for (int t = 0; t < SLEN; ++t) {
    const int pp = t & 1;

    // token + zx gather hoisted (independent loads, hide L2 latency)
    int tok[4];
    #pragma unroll
    for (int j = 0; j < 4; ++j)
      tok[j] = tokens[(b0 + row4 + j) * SLEN + t];
    float zxv[4][4];                      // [gate q][row j]
    #pragma unroll
    for (int j = 0; j < 4; ++j) {
      const float* zp = zx + (size_t)tok[j] * FOURH + colw;
      #pragma unroll
      for (int q = 0; q < 4; ++q) zxv[q][j] = zp[q * 256];
    }

    // A fragments: 8 x ds_read_b128, fully linear (conflict-free)
    bf16x8 a[8];
    #pragma unroll
    for (int s = 0; s < 8; ++s)
      a[s] = *reinterpret_cast<const bf16x8*>(&hbuf[pp][(s * 64 + l) * 8]);

    // 4 z-tiles (q, cb=w); B operands already in registers
    f32x4 acc[4];
    #pragma unroll
    for (int q = 0; q < 4; ++q) {
      f32x4 A = {0.f, 0.f, 0.f, 0.f};
      #pragma unroll
      for (int s = 0; s < 8; ++s)
        A = __builtin_amdgcn_mfma_f32_16x16x32_bf16(a[s], wf[q * 8 + s], A, 0, 0, 0);
      acc[q] = A;
    }

    // gates (fp32), c in regs, write h to out + next-step A-fragments
    #pragma unroll
    for (int j = 0; j < 4; ++j) {
      const float zi = acc[0][j] + zxv[0][j];
      const float zf = acc[1][j] + zxv[1][j];
      const float zo = acc[2][j] + zxv[2][j];
      const float zu = acc[3][j] + zxv[3][j];
      const float iv = sigmoid_(zi);
      const float fv = sigmoid_(zf);
      const float ov = sigmoid_(zo);
      const float uv = tanh_(zu);
      const float cn = iv * uv + fv * cst[j];
      cst[j] = cn;
      const float hn = ov * tanh_(cn);
      out[(size_t)(b0 + row4 + j) * (SLEN * HID) + (size_t)t * HID + colw] = hn;
      hbuf[pp ^ 1][((s4 * 4 + gg) * 16 + (row4 + j)) * 8 + jj] = f2bf(hn);
    }
    __syncthreads();   // single barrier/step (ping-pong makes it sufficient)
  }
}

extern "C" void kernel_launch(void* const* d_in, const int* in_sizes, int n_in,
                              void* d_out, int out_size, void* d_ws, size_t ws_size,
                              hipStream_t stream) {
  const int*   tokens = (const int*)d_in[0];
  const float* emb    = (const float*)d_in[1];
  const float* W      = (const float*)d_in[2];
  const float* b      = (const float*)d_in[3];
  float* out = (float*)d_out;

  float*          zx = (float*)d_ws;                                  // 512 KB
  unsigned short* Wb = (unsigned short*)((char*)d_ws + 512 * 1024);   // 512 KB

  lstm_prep<<<256, 256, 0, stream>>>(emb, W, b, zx, Wb);
  lstm_seq<<<16, 1024, 0, stream>>>(tokens, zx, Wb, out);
}